// Round 3
// baseline (220.910 us; speedup 1.0000x reference)
//
#include <hip/hip_runtime.h>
#include <math.h>

// ManifoldAlignmentLoss: B=256, D=512, N=50000, A=8, K=5
// Sparse fused strategy: mask density ~0.26% -> ~33K matched pairs.
// prep -> match_dot (LDS pair compaction + immediate dots) -> topk.

constexpr int D = 512;
constexpr int A = 8;
constexpr int K_NEI = 5;
constexpr int SLOTS = 512;         // per-b sim bucket capacity (mean ~130)
constexpr int CSTRIDE = 16;        // counter padding: 64B per counter line
constexpr int LDS_PAIR_CAP = 2048; // per-block pair cap (mean ~171, 100+ sigma)

__device__ __forceinline__ float wave_reduce_add(float v) {
    #pragma unroll
    for (int m = 1; m < 64; m <<= 1) v += __shfl_xor(v, m, 64);
    return v;
}

// ---------------- prep: normalize z rows, pack target attrs, zero state ----
// grid = B blocks x 64 threads
__global__ __launch_bounds__(64) void prep_kernel(
    const float* __restrict__ z, const int* __restrict__ tattr,
    float* __restrict__ z_norm, unsigned* __restrict__ tpacked,
    int* __restrict__ counters, float* __restrict__ out)
{
    const int b = blockIdx.x;
    const int lane = threadIdx.x;
    const float4* zrow = (const float4*)(z + (size_t)b * D);
    float4 v0 = zrow[lane * 2 + 0];
    float4 v1 = zrow[lane * 2 + 1];
    float ss = v0.x*v0.x + v0.y*v0.y + v0.z*v0.z + v0.w*v0.w
             + v1.x*v1.x + v1.y*v1.y + v1.z*v1.z + v1.w*v1.w;
    ss = wave_reduce_add(ss);
    const float scale = 1.0f / fmaxf(sqrtf(ss), 1e-12f);
    v0.x *= scale; v0.y *= scale; v0.z *= scale; v0.w *= scale;
    v1.x *= scale; v1.y *= scale; v1.z *= scale; v1.w *= scale;
    float4* orow = (float4*)(z_norm + (size_t)b * D);
    orow[lane * 2 + 0] = v0;
    orow[lane * 2 + 1] = v1;
    if (lane == 0) {
        unsigned p = 0;
        #pragma unroll
        for (int a = 0; a < A; a++)
            p |= ((unsigned)tattr[b * A + a] & 0xFu) << (4 * a);
        tpacked[b] = p;
        counters[b * CSTRIDE] = 0;
        if (b == 0) out[0] = 0.0f;
    }
}

// ------------- match_dot: per-block pair compaction + immediate dots -------
// grid = ceil(N/256) blocks x 256 threads
__global__ __launch_bounds__(256) void match_dot_kernel(
    const int* __restrict__ trattr, const unsigned* __restrict__ tpacked,
    const float* __restrict__ train, const float* __restrict__ z_norm,
    int* __restrict__ counters, float* __restrict__ simbuf, int N)
{
    __shared__ unsigned s_tp[256];
    __shared__ unsigned s_pairs[LDS_PAIR_CAP];
    __shared__ int s_cnt;

    const int tid = threadIdx.x;
    const int n = blockIdx.x * 256 + tid;
    s_tp[tid] = tpacked[tid];
    if (tid == 0) s_cnt = 0;
    __syncthreads();

    // ---- phase 1: match this thread's row against all 256 targets ----
    if (n < N) {
        const int4* a4 = (const int4*)(trattr + (size_t)n * A);
        const int4 x = a4[0], y = a4[1];
        const unsigned p =
             ((unsigned)x.x & 0xFu)        | (((unsigned)x.y & 0xFu) << 4)
           | (((unsigned)x.z & 0xFu) << 8)  | (((unsigned)x.w & 0xFu) << 12)
           | (((unsigned)y.x & 0xFu) << 16) | (((unsigned)y.y & 0xFu) << 20)
           | (((unsigned)y.z & 0xFu) << 24) | (((unsigned)y.w & 0xFu) << 28);

        const uint4* tp4 = (const uint4*)s_tp;
        #pragma unroll 4
        for (int bq = 0; bq < 64; bq++) {
            const uint4 t = tp4[bq];
            #pragma unroll
            for (int j = 0; j < 4; j++) {
                const unsigned tv = (j == 0) ? t.x : (j == 1) ? t.y : (j == 2) ? t.z : t.w;
                const unsigned yv = p ^ tv;
                // hi bit of each nibble set iff nibble nonzero
                const unsigned nzhi = ((((yv & 0x77777777u) + 0x77777777u) | yv) & 0x88888888u);
                if (__popc(nzhi) <= 1) {   // >= A-1 matching attrs
                    const int idx = atomicAdd(&s_cnt, 1);
                    if (idx < LDS_PAIR_CAP)
                        s_pairs[idx] = ((unsigned)n << 8) | (unsigned)(bq * 4 + j);
                }
            }
        }
    }
    __syncthreads();

    // ---- phase 2: block's 4 waves dot the compacted pairs ----
    const int cnt = min(s_cnt, LDS_PAIR_CAP);
    const int lane = tid & 63;
    const int w = tid >> 6;
    for (int i = w; i < cnt; i += 4) {
        const unsigned pr = s_pairs[i];
        const int nn = (int)(pr >> 8);
        const int b  = (int)(pr & 255u);
        const float4* row4 = (const float4*)(train + (size_t)nn * D);
        const float4* zr4  = (const float4*)(z_norm + (size_t)b * D);
        const float4 r0 = row4[lane * 2 + 0];
        const float4 r1 = row4[lane * 2 + 1];
        const float4 z0 = zr4[lane * 2 + 0];
        const float4 z1 = zr4[lane * 2 + 1];
        float ss = r0.x*r0.x + r0.y*r0.y + r0.z*r0.z + r0.w*r0.w
                 + r1.x*r1.x + r1.y*r1.y + r1.z*r1.z + r1.w*r1.w;
        float dd = r0.x*z0.x + r0.y*z0.y + r0.z*z0.z + r0.w*z0.w
                 + r1.x*z1.x + r1.y*z1.y + r1.z*z1.z + r1.w*z1.w;
        #pragma unroll
        for (int m = 1; m < 64; m <<= 1) {
            ss += __shfl_xor(ss, m, 64);
            dd += __shfl_xor(dd, m, 64);
        }
        if (lane == 0) {
            const float sim = dd / fmaxf(sqrtf(ss), 1e-12f);
            const int idx = atomicAdd(&counters[b * CSTRIDE], 1);
            if (idx < SLOTS) simbuf[(size_t)b * SLOTS + idx] = sim;
        }
    }
}

// ---------------- topk: one wave per b, 5x wave-max, atomic into out ------
// grid = 256 blocks x 64 threads
__global__ __launch_bounds__(64) void topk_kernel(
    const int* __restrict__ counters, const float* __restrict__ simbuf,
    float* __restrict__ out, int Bt)
{
    const int b = blockIdx.x;
    const int lane = threadIdx.x;
    const int cnt = counters[b * CSTRIDE];
    const int m = min(cnt, SLOTS);
    const float* buf = simbuf + (size_t)b * SLOTS;

    float v[8];
    #pragma unroll
    for (int k = 0; k < 8; k++) {
        const int i = lane + k * 64;
        v[k] = (i < m) ? buf[i] : -1e30f;
    }

    float s = 0.0f;
    #pragma unroll
    for (int r = 0; r < K_NEI; r++) {
        float best = v[0];
        #pragma unroll
        for (int k = 1; k < 8; k++) best = fmaxf(best, v[k]);
        float M = best;
        #pragma unroll
        for (int mm = 1; mm < 64; mm <<= 1) M = fmaxf(M, __shfl_xor(M, mm, 64));
        s += fmaxf(M, 0.0f);   // N-cnt exact zeros from unmatched entries dominate negatives
        const unsigned long long bal = __ballot(best == M);
        const int first = __ffsll(bal) - 1;
        if (lane == first) {
            if      (v[0] == M) v[0] = -1e30f;
            else if (v[1] == M) v[1] = -1e30f;
            else if (v[2] == M) v[2] = -1e30f;
            else if (v[3] == M) v[3] = -1e30f;
            else if (v[4] == M) v[4] = -1e30f;
            else if (v[5] == M) v[5] = -1e30f;
            else if (v[6] == M) v[6] = -1e30f;
            else                v[7] = -1e30f;
        }
    }

    if (lane == 0) {
        const float contrib = (cnt >= K_NEI) ? (1.0f - s * (1.0f / K_NEI)) : 0.0f;
        atomicAdd(out, contrib / (float)Bt);
    }
}

extern "C" void kernel_launch(void* const* d_in, const int* in_sizes, int n_in,
                              void* d_out, int out_size, void* d_ws, size_t ws_size,
                              hipStream_t stream)
{
    const float* z      = (const float*)d_in[0];   // [B, D] f32
    const int*   tattr  = (const int*)d_in[1];     // [B, A] i32
    const float* train  = (const float*)d_in[2];   // [N, D] f32
    const int*   trattr = (const int*)d_in[3];     // [N, A] i32
    float* out = (float*)d_out;

    const int B = in_sizes[0] / D;     // 256
    const int N = in_sizes[2] / D;     // 50000

    // ws layout
    char* ws = (char*)d_ws;
    float*    z_norm   = (float*)ws;    ws += (size_t)B * D * sizeof(float);
    unsigned* tpacked  = (unsigned*)ws; ws += (size_t)B * sizeof(unsigned);
    int*      counters = (int*)ws;      ws += (size_t)B * CSTRIDE * sizeof(int);
    float*    simbuf   = (float*)ws;

    prep_kernel<<<B, 64, 0, stream>>>(z, tattr, z_norm, tpacked, counters, out);
    match_dot_kernel<<<(N + 255) / 256, 256, 0, stream>>>(
        trattr, tpacked, train, z_norm, counters, simbuf, N);
    topk_kernel<<<B, 64, 0, stream>>>(counters, simbuf, out, B);
}

// Round 4
// 177.545 us; speedup vs baseline: 1.2442x; 1.2442x over previous
//
#include <hip/hip_runtime.h>
#include <math.h>

// ManifoldAlignmentLoss: B=256, D=512, N=50000, A=8, K=5
// Sparse pair-list strategy (R2 structure) + latency-optimized dot:
//   prep -> match (pair compaction) -> dot (8192 waves, 2-deep pipeline) -> topk
// R3 lesson: fusing match+dot starves the grid (196 blocks < 256 CUs -> 7% occ,
// 4.5% HBM). Keep dot as its own wide grid-stride kernel.

constexpr int D = 512;
constexpr int A = 8;
constexpr int K_NEI = 5;
constexpr int SLOTS = 512;        // per-b sim bucket capacity (mean ~130)
constexpr int CSTRIDE = 16;       // counter padding: 64B per counter line
constexpr int PAIR_CAP = 65536;   // global pair list capacity (mean ~33K)
constexpr int LDS_PAIR_CAP = 1024;
constexpr int DOT_BLOCKS = 2048;  // 8192 waves -> 32 waves/CU, ~4 pairs/wave

__device__ __forceinline__ float wave_reduce_add(float v) {
    #pragma unroll
    for (int m = 1; m < 64; m <<= 1) v += __shfl_xor(v, m, 64);
    return v;
}

// ---------------- prep: normalize z rows, pack target attrs, zero state ----
// grid = B blocks x 64 threads
__global__ __launch_bounds__(64) void prep_kernel(
    const float* __restrict__ z, const int* __restrict__ tattr,
    float* __restrict__ z_norm, unsigned* __restrict__ tpacked,
    int* __restrict__ counters, int* __restrict__ npairs,
    float* __restrict__ out)
{
    const int b = blockIdx.x;
    const int lane = threadIdx.x;
    const float4* zrow = (const float4*)(z + (size_t)b * D);
    float4 v0 = zrow[lane * 2 + 0];
    float4 v1 = zrow[lane * 2 + 1];
    float ss = v0.x*v0.x + v0.y*v0.y + v0.z*v0.z + v0.w*v0.w
             + v1.x*v1.x + v1.y*v1.y + v1.z*v1.z + v1.w*v1.w;
    ss = wave_reduce_add(ss);
    const float scale = 1.0f / fmaxf(sqrtf(ss), 1e-12f);
    v0.x *= scale; v0.y *= scale; v0.z *= scale; v0.w *= scale;
    v1.x *= scale; v1.y *= scale; v1.z *= scale; v1.w *= scale;
    float4* orow = (float4*)(z_norm + (size_t)b * D);
    orow[lane * 2 + 0] = v0;
    orow[lane * 2 + 1] = v1;
    if (lane == 0) {
        unsigned p = 0;
        #pragma unroll
        for (int a = 0; a < A; a++)
            p |= ((unsigned)tattr[b * A + a] & 0xFu) << (4 * a);
        tpacked[b] = p;
        counters[b * CSTRIDE] = 0;
        if (b == 0) { *npairs = 0; out[0] = 0.0f; }
    }
}

// ---------------- match: one thread per train row, compact pairs ----------
// grid = ceil(N/256) blocks x 256 threads
__global__ __launch_bounds__(256) void match_kernel(
    const int* __restrict__ trattr, const unsigned* __restrict__ tpacked,
    unsigned* __restrict__ pairs, int* __restrict__ npairs, int N)
{
    __shared__ unsigned s_tp[256];
    __shared__ unsigned s_pairs[LDS_PAIR_CAP];
    __shared__ int s_cnt, s_base;

    const int tid = threadIdx.x;
    const int n = blockIdx.x * 256 + tid;
    s_tp[tid] = tpacked[tid];
    if (tid == 0) s_cnt = 0;
    __syncthreads();

    if (n < N) {
        const int4* a4 = (const int4*)(trattr + (size_t)n * A);
        const int4 x = a4[0], y = a4[1];
        const unsigned p =
             ((unsigned)x.x & 0xFu)        | (((unsigned)x.y & 0xFu) << 4)
           | (((unsigned)x.z & 0xFu) << 8)  | (((unsigned)x.w & 0xFu) << 12)
           | (((unsigned)y.x & 0xFu) << 16) | (((unsigned)y.y & 0xFu) << 20)
           | (((unsigned)y.z & 0xFu) << 24) | (((unsigned)y.w & 0xFu) << 28);

        const uint4* tp4 = (const uint4*)s_tp;
        #pragma unroll 4
        for (int bq = 0; bq < 64; bq++) {
            const uint4 t = tp4[bq];
            #pragma unroll
            for (int j = 0; j < 4; j++) {
                const unsigned tv = (j == 0) ? t.x : (j == 1) ? t.y : (j == 2) ? t.z : t.w;
                const unsigned yv = p ^ tv;
                // hi bit of each nibble set iff nibble nonzero
                const unsigned nzhi = ((((yv & 0x77777777u) + 0x77777777u) | yv) & 0x88888888u);
                if (__popc(nzhi) <= 1) {   // >= A-1 matching attrs
                    const int idx = atomicAdd(&s_cnt, 1);
                    if (idx < LDS_PAIR_CAP)
                        s_pairs[idx] = ((unsigned)n << 8) | (unsigned)(bq * 4 + j);
                }
            }
        }
    }
    __syncthreads();
    const int cnt = min(s_cnt, LDS_PAIR_CAP);
    if (tid == 0) s_base = atomicAdd(npairs, cnt);
    __syncthreads();
    const int base = s_base;
    for (int i = tid; i < cnt; i += 256)
        if (base + i < PAIR_CAP) pairs[base + i] = s_pairs[i];
}

// ---------------- dot: one wave per pair, 2-deep software pipeline --------
// grid = DOT_BLOCKS x 256 threads
__global__ __launch_bounds__(256) void dot_kernel(
    const float* __restrict__ train, const float* __restrict__ z_norm,
    const unsigned* __restrict__ pairs, const int* __restrict__ npairs,
    int* __restrict__ counters, float* __restrict__ simbuf)
{
    const int lane = threadIdx.x & 63;
    const int w = blockIdx.x * 4 + (threadIdx.x >> 6);
    const int nwaves = DOT_BLOCKS * 4;
    const int np = min(*npairs, PAIR_CAP);

    // iteration count for this wave; all pair indices pre-loaded (lane t holds iter t)
    const int niter = (np - w + nwaves - 1) / nwaves;   // may be <= 0
    if (niter <= 0) return;
    const int myidx = w + lane * nwaves;
    const unsigned mypr = (myidx < np && lane < niter) ? pairs[myidx] : 0u;

    // --- prologue: issue loads for iteration 0 ---
    unsigned pr = __shfl(mypr, 0, 64);
    const float4* row4 = (const float4*)(train  + (size_t)(pr >> 8)   * D);
    const float4* zr4  = (const float4*)(z_norm + (size_t)(pr & 255u) * D);
    float4 r0 = row4[lane * 2 + 0];
    float4 r1 = row4[lane * 2 + 1];
    float4 z0 = zr4[lane * 2 + 0];
    float4 z1 = zr4[lane * 2 + 1];

    for (int t = 0; t < niter; t++) {
        // --- prefetch iteration t+1 while reducing t ---
        float4 nr0, nr1, nz0, nz1;
        const bool more = (t + 1 < niter);
        if (more) {
            const unsigned npr = __shfl(mypr, t + 1, 64);
            const float4* nrow4 = (const float4*)(train  + (size_t)(npr >> 8)   * D);
            const float4* nzr4  = (const float4*)(z_norm + (size_t)(npr & 255u) * D);
            nr0 = nrow4[lane * 2 + 0];
            nr1 = nrow4[lane * 2 + 1];
            nz0 = nzr4[lane * 2 + 0];
            nz1 = nzr4[lane * 2 + 1];
        }

        float ss = r0.x*r0.x + r0.y*r0.y + r0.z*r0.z + r0.w*r0.w
                 + r1.x*r1.x + r1.y*r1.y + r1.z*r1.z + r1.w*r1.w;
        float dd = r0.x*z0.x + r0.y*z0.y + r0.z*z0.z + r0.w*z0.w
                 + r1.x*z1.x + r1.y*z1.y + r1.z*z1.z + r1.w*z1.w;
        #pragma unroll
        for (int m = 1; m < 64; m <<= 1) {
            ss += __shfl_xor(ss, m, 64);
            dd += __shfl_xor(dd, m, 64);
        }
        if (lane == 0) {
            const int b = (int)(pr & 255u);
            const float sim = dd / fmaxf(sqrtf(ss), 1e-12f);
            const int idx = atomicAdd(&counters[b * CSTRIDE], 1);
            if (idx < SLOTS) simbuf[(size_t)b * SLOTS + idx] = sim;
        }

        if (more) {
            pr = __shfl(mypr, t + 1, 64);
            r0 = nr0; r1 = nr1; z0 = nz0; z1 = nz1;
        }
    }
}

// ---------------- topk: one wave per b, 5x wave-max, atomic into out ------
// grid = 256 blocks x 64 threads
__global__ __launch_bounds__(64) void topk_kernel(
    const int* __restrict__ counters, const float* __restrict__ simbuf,
    float* __restrict__ out, int Bt)
{
    const int b = blockIdx.x;
    const int lane = threadIdx.x;
    const int cnt = counters[b * CSTRIDE];
    const int m = min(cnt, SLOTS);
    const float* buf = simbuf + (size_t)b * SLOTS;

    float v[8];
    #pragma unroll
    for (int k = 0; k < 8; k++) {
        const int i = lane + k * 64;
        v[k] = (i < m) ? buf[i] : -1e30f;
    }

    float s = 0.0f;
    #pragma unroll
    for (int r = 0; r < K_NEI; r++) {
        float best = v[0];
        #pragma unroll
        for (int k = 1; k < 8; k++) best = fmaxf(best, v[k]);
        float M = best;
        #pragma unroll
        for (int mm = 1; mm < 64; mm <<= 1) M = fmaxf(M, __shfl_xor(M, mm, 64));
        s += fmaxf(M, 0.0f);   // N-cnt exact zeros from unmatched entries dominate negatives
        const unsigned long long bal = __ballot(best == M);
        const int first = __ffsll(bal) - 1;
        if (lane == first) {
            if      (v[0] == M) v[0] = -1e30f;
            else if (v[1] == M) v[1] = -1e30f;
            else if (v[2] == M) v[2] = -1e30f;
            else if (v[3] == M) v[3] = -1e30f;
            else if (v[4] == M) v[4] = -1e30f;
            else if (v[5] == M) v[5] = -1e30f;
            else if (v[6] == M) v[6] = -1e30f;
            else                v[7] = -1e30f;
        }
    }

    if (lane == 0) {
        const float contrib = (cnt >= K_NEI) ? (1.0f - s * (1.0f / K_NEI)) : 0.0f;
        atomicAdd(out, contrib / (float)Bt);
    }
}

extern "C" void kernel_launch(void* const* d_in, const int* in_sizes, int n_in,
                              void* d_out, int out_size, void* d_ws, size_t ws_size,
                              hipStream_t stream)
{
    const float* z      = (const float*)d_in[0];   // [B, D] f32
    const int*   tattr  = (const int*)d_in[1];     // [B, A] i32
    const float* train  = (const float*)d_in[2];   // [N, D] f32
    const int*   trattr = (const int*)d_in[3];     // [N, A] i32
    float* out = (float*)d_out;

    const int B = in_sizes[0] / D;     // 256
    const int N = in_sizes[2] / D;     // 50000

    // ws layout
    char* ws = (char*)d_ws;
    float*    z_norm   = (float*)ws;    ws += (size_t)B * D * sizeof(float);
    unsigned* tpacked  = (unsigned*)ws; ws += (size_t)B * sizeof(unsigned);
    int*      counters = (int*)ws;      ws += (size_t)B * CSTRIDE * sizeof(int);
    float*    simbuf   = (float*)ws;    ws += (size_t)B * SLOTS * sizeof(float);
    int*      npairs   = (int*)ws;      ws += 64;
    unsigned* pairs    = (unsigned*)ws;

    prep_kernel<<<B, 64, 0, stream>>>(z, tattr, z_norm, tpacked, counters, npairs, out);
    match_kernel<<<(N + 255) / 256, 256, 0, stream>>>(trattr, tpacked, pairs, npairs, N);
    dot_kernel<<<DOT_BLOCKS, 256, 0, stream>>>(train, z_norm, pairs, npairs, counters, simbuf);
    topk_kernel<<<B, 64, 0, stream>>>(counters, simbuf, out, B);
}